// Round 6
// baseline (118177.136 us; speedup 1.0000x reference)
//
#include <hip/hip_runtime.h>

#define SCOPE_AGENT __HIP_MEMORY_SCOPE_AGENT

// ws layout (float offsets)
#define OFF_HS    0          // [2][512][64] hidden states
#define OFF_HP    65536      // [2][512][64] per-layer h'
#define OFF_SG    131072     // [2][512][64] per-layer sorted
#define OFF_U     196608     // [2][1024][64] per-layer u = relu(M [h;s])
#define OFF_CTR   327680     // barrier: flag[256] lines (uint stride 32), genr[16] lines
#define OFF_T1    393216     // [2][1024][1024] compose scratch
#define OFF_M     2490368    // [2][1024][1024] composed M
#define OFF_GIX   4587520    // [512][512][3][64] precomputed W_ih. x_t (layer 0)
#define OFF_XT    4587520    // fallback: [512][512][64] transposed x
#define WS_GIX    54919168   // floats incl gix (~220 MB)
#define WS_XT     21364736   // floats incl xT (~85 MB)

__device__ __forceinline__ float sigm(float x) { return 1.f / (1.f + expf(-x)); }

__device__ __forceinline__ float ld_sc1(const float* p) {
    return __hip_atomic_load(p, __ATOMIC_RELAXED, SCOPE_AGENT);
}
__device__ __forceinline__ void st_sc1(float* p, float v) {
    __hip_atomic_store(p, v, __ATOMIC_RELAXED, SCOPE_AGENT);
}

// Single-scanner generation barrier (no atomics, no resets). 256 participants.
__device__ __forceinline__ void gbar(unsigned* flags, unsigned* genr, unsigned g) {
    __syncthreads();
    const int tid = threadIdx.x;
    if (blockIdx.x == 0) {
        if (tid >= 1 && tid < 256) {
            while (__hip_atomic_load(&flags[tid << 5], __ATOMIC_RELAXED, SCOPE_AGENT) < g)
                __builtin_amdgcn_s_sleep(1);
        }
        __syncthreads();
        if (tid < 16)
            __hip_atomic_store(&genr[tid << 5], g, __ATOMIC_RELAXED, SCOPE_AGENT);
        __syncthreads();
    } else {
        if (tid == 0) {
            __hip_atomic_store(&flags[blockIdx.x << 5], g, __ATOMIC_RELAXED, SCOPE_AGENT);
            while (__hip_atomic_load(&genr[(blockIdx.x & 15) << 5], __ATOMIC_RELAXED, SCOPE_AGENT) < g)
                __builtin_amdgcn_s_sleep(1);
        }
        __syncthreads();
    }
}

__global__ void k_init(const float* __restrict__ h0, float* __restrict__ ws) {
    int idx = blockIdx.x * blockDim.x + threadIdx.x;   // 65536
    int l = idx >> 15, k = (idx & 32767) >> 6;
    ws[OFF_HS + idx] = h0[(l << 9) + k];
    if (idx < 8704) ((unsigned*)(ws + OFF_CTR))[idx] = 0u;
}

// gix[t][j][g][b] = sum_k wih0[g*512+j][k] * x[b][t*512+k]
__global__ void k_gix(const float* __restrict__ x, const float* __restrict__ wih,
                      float* __restrict__ gix) {
    __shared__ float xs[128][65];
    __shared__ float ww[32][129];
    int t = blockIdx.x, rb = blockIdx.y * 32;
    int tid = threadIdx.x;
    int rw = tid >> 6, b = tid & 63;
    float acc[8] = {0.f, 0.f, 0.f, 0.f, 0.f, 0.f, 0.f, 0.f};
    for (int kc = 0; kc < 4; kc++) {
        __syncthreads();
        for (int i = tid; i < 8192; i += 256) {
            int k = i & 127, b2 = i >> 7;
            xs[k][b2] = x[(size_t)b2 * 262144 + (size_t)t * 512 + kc * 128 + k];
        }
        for (int i = tid; i < 4096; i += 256) {
            int r = i >> 7, k = i & 127;
            ww[r][k] = wih[(size_t)(rb + r) * 512 + kc * 128 + k];
        }
        __syncthreads();
        for (int k = 0; k < 128; k++) {
            float xv = xs[k][b];
#pragma unroll
            for (int rr = 0; rr < 8; rr++)
                acc[rr] = fmaf(ww[rw * 8 + rr][k], xv, acc[rr]);
        }
    }
#pragma unroll
    for (int rr = 0; rr < 8; rr++) {
        int rg = rb + rw * 8 + rr;
        int g = rg >> 9, j = rg & 511;
        gix[((size_t)((size_t)t * 512 + j) * 3 + g) * 64 + b] = acc[rr];
    }
}

// fallback transpose x -> xT[t][k][b]
__global__ void k_xtk(const float* __restrict__ x, float* __restrict__ xT) {
    __shared__ float tile[64][65];
    int t = blockIdx.x >> 3, kc = blockIdx.x & 7;
    int k = threadIdx.x & 63, b0 = threadIdx.x >> 6;
    for (int i = 0; i < 16; i++) {
        int b = i * 4 + b0;
        tile[k][b] = x[(size_t)b * 262144 + (size_t)t * 512 + kc * 64 + k];
    }
    __syncthreads();
    int b2 = threadIdx.x & 63, k0 = threadIdx.x >> 6;
    for (int i = 0; i < 16; i++) {
        int k2 = i * 4 + k0;
        xT[((size_t)t * 512 + kc * 64 + k2) * 64 + b2] = tile[k2][b2];
    }
}

// T1 = C2p * C1
__global__ void k_t1(const float* __restrict__ a1, const float* __restrict__ a2,
                     float* __restrict__ T1) {
    int l = blockIdx.x >> 10, c = blockIdx.x & 1023;
    int g = c >> 8, jj = c & 255;
    __shared__ float sA2[256];
    sA2[threadIdx.x] = a2[l * 65536 + jj * 256 + threadIdx.x];
    __syncthreads();
    const float* A1l = a1 + l * 262144;
    for (int colq = 0; colq < 4; colq++) {
        int col = colq * 256 + threadIdx.x;
        int half = col >> 9, cm = col & 511;
        float acc = 0.f;
#pragma unroll 4
        for (int q = 0; q < 64; q++) {
            int a0 = 2 * half;
            int j0 = g * 64 + q;
            acc = fmaf(sA2[4 * q + a0],     A1l[j0 * 512 + cm], acc);
            acc = fmaf(sA2[4 * q + a0 + 1], A1l[(j0 + 256) * 512 + cm], acc);
        }
        T1[((size_t)(l << 10) + c) * 1024 + col] = acc;
    }
}

// M = C3p * T1
__global__ void k_m(const float* __restrict__ a3, const float* __restrict__ T1,
                    float* __restrict__ M) {
    int l = blockIdx.x >> 10, c = blockIdx.x & 1023;
    int g = c >> 8, jj = c & 255;
    __shared__ float sA3[256];
    sA3[threadIdx.x] = a3[l * 65536 + jj * 256 + threadIdx.x];
    __syncthreads();
    const float* T1l = T1 + ((size_t)l << 20);
    for (int colq = 0; colq < 4; colq++) {
        int col = colq * 256 + threadIdx.x;
        float acc = 0.f;
#pragma unroll 4
        for (int m = 0; m < 256; m++) {
            int p = ((m & 3) << 8) + (g << 6) + (m >> 2);
            acc = fmaf(sA3[m], T1l[p * 1024 + col], acc);
        }
        M[((size_t)(l << 10) + c) * 1024 + col] = acc;
    }
}

// Persistent cooperative kernel. 256 blocks x 1024 threads, block owns 2 features.
// LOAD-BATCHED stages: each stage issues its full set of sc1 loads into
// compile-time-indexed register arrays BEFORE consuming any (sc1 bypasses
// L1/L2 -> ~0.8us/round-trip; at VGPR=64 the compiler could only keep ~8-16
// in flight -> 4-8 serialized latency rounds per stage = the measured ghost).
// __launch_bounds__(1024,4): cap VGPR at 128 (exactly 16 waves/CU).
__global__ void __launch_bounds__(1024, 4)
persist(const float* __restrict__ x, const float* __restrict__ xT,
        const float* __restrict__ gix, int has_xt, int has_gix,
        const float* __restrict__ wih, const float* __restrict__ whh,
        const float* __restrict__ bih, const float* __restrict__ bhh,
        const float* __restrict__ Mc, const float* __restrict__ a4,
        float* __restrict__ ws, float* __restrict__ out) {
    __shared__ float wA[2][2][6][512];   // [l][f][d] d = gate*2+side (0=in,1=h)
    __shared__ float wM[2][4][1024];
    __shared__ float wD[2][2][1024];
    __shared__ float red2[12][16][64];
    __shared__ float bb[2][2][4];
    __shared__ float sH[2][2][64];       // [l][f][lane]

    const int tid = threadIdx.x, w = tid >> 6, lane = tid & 63, bid = blockIdx.x;

    for (int i = tid; i < 12288; i += 1024) {
        int l = i / 6144, r = i % 6144, f = r / 3072, r2 = r % 3072, d = r2 / 512, k = r2 & 511;
        int gate = d >> 1, side = d & 1;
        int j = 2 * bid + f;
        const float* src = side ? whh : wih;
        wA[l][f][d][k] = src[l * 786432 + (gate * 512 + j) * 512 + k];
    }
    for (int i = tid; i < 8192; i += 1024) {
        int l = i >> 12, r = (i >> 10) & 3, col = i & 1023;
        wM[l][r][col] = Mc[((size_t)(l << 10) + 4 * bid + r) * 1024 + col];
    }
    for (int i = tid; i < 4096; i += 1024) {
        int l = i >> 11, f = (i >> 10) & 1, k = i & 1023;
        wD[l][f][k] = a4[l * 524288 + (2 * bid + f) * 1024 + k];
    }
    if (tid < 16) {
        int l = tid / 8, f = (tid / 4) & 1, g = tid & 3;
        int j = 2 * bid + f;
        float v;
        if (g == 0)      v = bih[l * 1536 + j] + bhh[l * 1536 + j];
        else if (g == 1) v = bih[l * 1536 + 512 + j] + bhh[l * 1536 + 512 + j];
        else if (g == 2) v = bih[l * 1536 + 1024 + j];
        else             v = bhh[l * 1536 + 1024 + j];
        bb[l][f][g] = v;
    }
    __syncthreads();

    float* hsG = ws + OFF_HS;
    float* hPg = ws + OFF_HP;    // [l][512][64]
    float* sGg = ws + OFF_SG;    // [l][512][64]
    float* uG  = ws + OFF_U;     // [l][1024][64]
    unsigned* flags = (unsigned*)(ws + OFF_CTR);   // 256 lines
    unsigned* genr  = flags + 8192;                // 16 lines
    unsigned bgen = 0;

    // ---- Stage A: GRU gates + h' ----
    auto stageA = [&](int l, int t) {
        float hprev = 0.f;
        if (w < 2) hprev = ld_sc1(&hsG[l * 32768 + (2 * bid + w) * 64 + lane]);
        const float* hb = hsG + l * 32768;
        float* hPl = hPg + l * 32768;
        int k0 = w * 32;
        if (l == 0 && has_gix) {
            float hv[32];
#pragma unroll
            for (int kk = 0; kk < 32; kk++)
                hv[kk] = ld_sc1(&hb[(k0 + kk) * 64 + lane]);
            float acc[6] = {0.f, 0.f, 0.f, 0.f, 0.f, 0.f};
#pragma unroll
            for (int kk = 0; kk < 32; kk++) {
                int k = k0 + kk;
#pragma unroll
                for (int f = 0; f < 2; f++) {
                    acc[f * 3 + 0] = fmaf(wA[0][f][1][k], hv[kk], acc[f * 3 + 0]);
                    acc[f * 3 + 1] = fmaf(wA[0][f][3][k], hv[kk], acc[f * 3 + 1]);
                    acc[f * 3 + 2] = fmaf(wA[0][f][5][k], hv[kk], acc[f * 3 + 2]);
                }
            }
#pragma unroll
            for (int u = 0; u < 6; u++) red2[u][w][lane] = acc[u];
            __syncthreads();
            if (w < 2) {
                int f = w, j = 2 * bid + f;
                float s0 = 0, s1 = 0, s2 = 0;
#pragma unroll
                for (int i = 0; i < 16; i++) {
                    s0 += red2[f * 3 + 0][i][lane];
                    s1 += red2[f * 3 + 1][i][lane];
                    s2 += red2[f * 3 + 2][i][lane];
                }
                const float* gx = gix + ((size_t)((size_t)t * 512 + j) * 3) * 64;
                float r = sigm(gx[lane] + s0 + bb[0][f][0]);
                float z = sigm(gx[64 + lane] + s1 + bb[0][f][1]);
                float n = tanhf(gx[128 + lane] + bb[0][f][2] + r * (s2 + bb[0][f][3]));
                float hp = (1.f - z) * n + z * hprev;
                sH[0][f][lane] = hp;
                st_sc1(&hPl[j * 64 + lane], hp);
            }
        } else {
            float ivv[32], hvv[32];
#pragma unroll
            for (int kk = 0; kk < 32; kk++) {
                int k = k0 + kk;
                if (l == 1)       ivv[kk] = ld_sc1(&hsG[k * 64 + lane]);
                else if (has_xt)  ivv[kk] = xT[(size_t)t * 32768 + k * 64 + lane];
                else              ivv[kk] = x[(size_t)lane * 262144 + (size_t)t * 512 + k];
                hvv[kk] = ld_sc1(&hb[k * 64 + lane]);
            }
            float acc[12];
#pragma unroll
            for (int u = 0; u < 12; u++) acc[u] = 0.f;
#pragma unroll
            for (int kk = 0; kk < 32; kk++) {
                int k = k0 + kk;
#pragma unroll
                for (int f = 0; f < 2; f++) {
                    acc[f * 6 + 0] = fmaf(wA[l][f][0][k], ivv[kk], acc[f * 6 + 0]);
                    acc[f * 6 + 1] = fmaf(wA[l][f][1][k], hvv[kk], acc[f * 6 + 1]);
                    acc[f * 6 + 2] = fmaf(wA[l][f][2][k], ivv[kk], acc[f * 6 + 2]);
                    acc[f * 6 + 3] = fmaf(wA[l][f][3][k], hvv[kk], acc[f * 6 + 3]);
                    acc[f * 6 + 4] = fmaf(wA[l][f][4][k], ivv[kk], acc[f * 6 + 4]);
                    acc[f * 6 + 5] = fmaf(wA[l][f][5][k], hvv[kk], acc[f * 6 + 5]);
                }
            }
#pragma unroll
            for (int u = 0; u < 12; u++) red2[u][w][lane] = acc[u];
            __syncthreads();
            if (w < 2) {
                int f = w, j = 2 * bid + f;
                float g0 = 0, g1 = 0, g2 = 0, g3 = 0, g4 = 0, g5 = 0;
#pragma unroll
                for (int i = 0; i < 16; i++) {
                    g0 += red2[f * 6 + 0][i][lane]; g1 += red2[f * 6 + 1][i][lane];
                    g2 += red2[f * 6 + 2][i][lane]; g3 += red2[f * 6 + 3][i][lane];
                    g4 += red2[f * 6 + 4][i][lane]; g5 += red2[f * 6 + 5][i][lane];
                }
                float r = sigm(g0 + g1 + bb[l][f][0]);
                float z = sigm(g2 + g3 + bb[l][f][1]);
                float n = tanhf(g4 + bb[l][f][2] + r * (g5 + bb[l][f][3]));
                float hp = (1.f - z) * n + z * hprev;
                sH[l][f][lane] = hp;
                st_sc1(&hPl[j * 64 + lane], hp);
            }
        }
    };

    // ---- Stage B: rank of both block features over one 32-chunk per wave ----
    auto stageB = [&](int l) {
        int j0 = 2 * bid, j1 = j0 + 1;
        float v0 = sH[l][0][lane], v1 = sH[l][1][lane];
        const float* hPl = hPg + l * 32768;
        float* sGl = sGg + l * 32768;
        int k0 = w * 32;
        float hv[32];
#pragma unroll
        for (int kk = 0; kk < 32; kk++)
            hv[kk] = ld_sc1(&hPl[(k0 + kk) * 64 + lane]);
        int cnt0 = 0, cnt1 = 0;
#pragma unroll
        for (int kk = 0; kk < 32; kk++) {
            int k = k0 + kk;
            cnt0 += (hv[kk] < v0 || (hv[kk] == v0 && k < j0)) ? 1 : 0;
            cnt1 += (hv[kk] < v1 || (hv[kk] == v1 && k < j1)) ? 1 : 0;
        }
        red2[0][w][lane] = (float)cnt0;
        red2[1][w][lane] = (float)cnt1;
        __syncthreads();
        if (w < 2) {
            int rk = 0;
#pragma unroll
            for (int i = 0; i < 16; i++) rk += (int)red2[w][i][lane];
            st_sc1(&sGl[rk * 64 + lane], sH[l][w][lane]);
        }
    };

    // ---- Stage C: u = relu(M [h; s]) ----
    auto stageC = [&](int l) {
        float acc[4] = {0.f, 0.f, 0.f, 0.f};
        int k0 = w * 64;
        const float* src = (k0 < 512) ? &hPg[l * 32768 + k0 * 64]
                                      : &sGg[l * 32768 + (k0 - 512) * 64];
#pragma unroll
        for (int rd = 0; rd < 2; rd++) {
            float vv[32];
#pragma unroll
            for (int kk = 0; kk < 32; kk++)
                vv[kk] = ld_sc1(&src[(rd * 32 + kk) * 64 + lane]);
#pragma unroll
            for (int kk = 0; kk < 32; kk++) {
                int k = k0 + rd * 32 + kk;
#pragma unroll
                for (int r = 0; r < 4; r++)
                    acc[r] = fmaf(wM[l][r][k], vv[kk], acc[r]);
            }
        }
#pragma unroll
        for (int r = 0; r < 4; r++) red2[r][w][lane] = acc[r];
        __syncthreads();
        if (w < 4) {
            float s = 0.f;
#pragma unroll
            for (int i = 0; i < 16; i++) s += red2[w][i][lane];
            st_sc1(&uG[l * 65536 + (4 * bid + w) * 64 + lane], fmaxf(s, 0.f));
        }
    };

    // ---- Stage D: scores + state update ----
    auto stageD = [&](int l, int t) {
        float a0 = 0.f, a1v = 0.f;
        int k0 = w * 64;
        const float* uL = uG + l * 65536;
#pragma unroll
        for (int rd = 0; rd < 2; rd++) {
            float vv[32];
#pragma unroll
            for (int kk = 0; kk < 32; kk++)
                vv[kk] = ld_sc1(&uL[(k0 + rd * 32 + kk) * 64 + lane]);
#pragma unroll
            for (int kk = 0; kk < 32; kk++) {
                int k = k0 + rd * 32 + kk;
                a0 = fmaf(wD[l][0][k], vv[kk], a0);
                a1v = fmaf(wD[l][1][k], vv[kk], a1v);
            }
        }
        red2[0][w][lane] = a0;
        red2[1][w][lane] = a1v;
        __syncthreads();
        if (w < 2) {
            float s = 0.f;
#pragma unroll
            for (int i = 0; i < 16; i++) s += red2[w][i][lane];
            float hnew = sH[l][w][lane] * sigm(s);
            st_sc1(&hsG[l * 32768 + (2 * bid + w) * 64 + lane], hnew);
            if (l == 1)
                out[(size_t)lane * 262144 + (size_t)t * 512 + (2 * bid + w)] = hnew;
        }
    };

    // Pipelined main loop: iteration t runs (layer0, t) and (layer1, t-1).
    for (int t = 0; t <= 512; t++) {
        const int t0 = t, t1 = t - 1;
        const bool do0 = (t0 < 512), do1 = (t1 >= 0);

        if (do0) stageA(0, t0);
        if (do1) { __syncthreads(); stageA(1, t1); }
        gbar(flags, genr, ++bgen);

        if (do0) stageB(0);
        if (do1) { __syncthreads(); stageB(1); }
        gbar(flags, genr, ++bgen);

        if (do0) stageC(0);
        if (do1) { __syncthreads(); stageC(1); }
        gbar(flags, genr, ++bgen);

        if (do0) stageD(0, t0);
        if (do1) { __syncthreads(); stageD(1, t1); }
        gbar(flags, genr, ++bgen);
    }
}

extern "C" void kernel_launch(void* const* d_in, const int* in_sizes, int n_in,
                              void* d_out, int out_size, void* d_ws, size_t ws_size,
                              hipStream_t stream) {
    const float* x   = (const float*)d_in[0];
    const float* h0  = (const float*)d_in[1];
    const float* wih = (const float*)d_in[2];
    const float* whh = (const float*)d_in[3];
    const float* bih = (const float*)d_in[4];
    const float* bhh = (const float*)d_in[5];
    const float* a1  = (const float*)d_in[6];
    const float* a2  = (const float*)d_in[7];
    const float* a3  = (const float*)d_in[8];
    const float* a4  = (const float*)d_in[9];
    float* ws  = (float*)d_ws;
    float* out = (float*)d_out;

    int has_gix = (ws_size >= (size_t)WS_GIX * 4) ? 1 : 0;
    int has_xt  = (!has_gix && ws_size >= (size_t)WS_XT * 4) ? 1 : 0;
    float* T1p = ws + OFF_T1;
    float* Mp  = ws + OFF_M;
    const float* gixp = ws + OFF_GIX;
    const float* xTp  = ws + OFF_XT;

    hipLaunchKernelGGL(k_init, dim3(256), dim3(256), 0, stream, h0, ws);
    if (has_gix)
        hipLaunchKernelGGL(k_gix, dim3(512, 48), dim3(256), 0, stream, x, wih, ws + OFF_GIX);
    else if (has_xt)
        hipLaunchKernelGGL(k_xtk, dim3(4096), dim3(256), 0, stream, x, ws + OFF_XT);
    hipLaunchKernelGGL(k_t1, dim3(2048), dim3(256), 0, stream, a1, a2, T1p);
    hipLaunchKernelGGL(k_m, dim3(2048), dim3(256), 0, stream, a3, T1p, Mp);

    void* args[] = {(void*)&x, (void*)&xTp, (void*)&gixp, (void*)&has_xt, (void*)&has_gix,
                    (void*)&wih, (void*)&whh, (void*)&bih, (void*)&bhh,
                    (void*)&Mp, (void*)&a4, (void*)&ws, (void*)&out};
    hipLaunchCooperativeKernel((void*)persist, dim3(256), dim3(1024), args, 0, stream);
}

// Round 7
// 45066.092 us; speedup vs baseline: 2.6223x; 2.6223x over previous
//
#include <hip/hip_runtime.h>

#define SCOPE_AGENT __HIP_MEMORY_SCOPE_AGENT

// ws layout (float offsets)
// PACKED exchange layout for hsG/hPg/uG: [dim/2][64 lanes][2] -> element (k,lane)
// at ((k>>1)*128 + lane*2 + (k&1)). Consumers load PAIRS with native 8B agent
// atomics (half the L3 requests, 2x bytes/request). sG stays [rk][lane] (4B).
#define OFF_HS    0          // [2] packed [256][64][2] hidden states
#define OFF_HP    65536      // [2] packed h'
#define OFF_SG    131072     // [2][512][64] per-layer sorted (unpacked)
#define OFF_U     196608     // [2] packed [512][64][2] u
#define OFF_CTR   327680     // barrier: flag[256] lines (uint stride 32), genr[16] lines
#define OFF_T1    393216     // [2][1024][1024] compose scratch
#define OFF_M     2490368    // [2][1024][1024] composed M
#define OFF_GIX   4587520    // [512][512][3][64] precomputed W_ih. x_t (layer 0)
#define OFF_XT    4587520    // fallback: [512][512][64] transposed x
#define WS_GIX    54919168   // floats incl gix (~220 MB)
#define WS_XT     21364736   // floats incl xT (~85 MB)

__device__ __forceinline__ float sigm(float x) { return 1.f / (1.f + expf(-x)); }

__device__ __forceinline__ float ld_sc1(const float* p) {
    return __hip_atomic_load(p, __ATOMIC_RELAXED, SCOPE_AGENT);
}
__device__ __forceinline__ void st_sc1(float* p, float v) {
    __hip_atomic_store(p, v, __ATOMIC_RELAXED, SCOPE_AGENT);
}
// 8B agent-scope pair load/store (element [0] at lower address)
__device__ __forceinline__ void ld2(const float* p, float& a, float& b) {
    unsigned long long v = __hip_atomic_load((const unsigned long long*)p,
                                             __ATOMIC_RELAXED, SCOPE_AGENT);
    a = __uint_as_float((unsigned)v);
    b = __uint_as_float((unsigned)(v >> 32));
}
__device__ __forceinline__ void st2(float* p, float a, float b) {
    unsigned long long v = ((unsigned long long)__float_as_uint(b) << 32) |
                           (unsigned long long)__float_as_uint(a);
    __hip_atomic_store((unsigned long long*)p, v, __ATOMIC_RELAXED, SCOPE_AGENT);
}

// Single-scanner generation barrier (no atomics, no resets). 256 participants.
__device__ __forceinline__ void gbar(unsigned* flags, unsigned* genr, unsigned g) {
    __syncthreads();
    const int tid = threadIdx.x;
    if (blockIdx.x == 0) {
        if (tid >= 1 && tid < 256) {
            while (__hip_atomic_load(&flags[tid << 5], __ATOMIC_RELAXED, SCOPE_AGENT) < g)
                __builtin_amdgcn_s_sleep(1);
        }
        __syncthreads();
        if (tid < 16)
            __hip_atomic_store(&genr[tid << 5], g, __ATOMIC_RELAXED, SCOPE_AGENT);
        __syncthreads();
    } else {
        if (tid == 0) {
            __hip_atomic_store(&flags[blockIdx.x << 5], g, __ATOMIC_RELAXED, SCOPE_AGENT);
            while (__hip_atomic_load(&genr[(blockIdx.x & 15) << 5], __ATOMIC_RELAXED, SCOPE_AGENT) < g)
                __builtin_amdgcn_s_sleep(1);
        }
        __syncthreads();
    }
}

__global__ void k_init(const float* __restrict__ h0, float* __restrict__ ws) {
    int idx = blockIdx.x * blockDim.x + threadIdx.x;   // 65536
    int l = idx >> 15, k = (idx & 32767) >> 6, lane = idx & 63;
    // packed store
    ws[OFF_HS + (l << 15) + ((k >> 1) << 7) + (lane << 1) + (k & 1)] = h0[(l << 9) + k];
    if (idx < 8704) ((unsigned*)(ws + OFF_CTR))[idx] = 0u;
}

// gix[t][j][g][b] = sum_k wih0[g*512+j][k] * x[b][t*512+k]
__global__ void k_gix(const float* __restrict__ x, const float* __restrict__ wih,
                      float* __restrict__ gix) {
    __shared__ float xs[128][65];
    __shared__ float ww[32][129];
    int t = blockIdx.x, rb = blockIdx.y * 32;
    int tid = threadIdx.x;
    int rw = tid >> 6, b = tid & 63;
    float acc[8] = {0.f, 0.f, 0.f, 0.f, 0.f, 0.f, 0.f, 0.f};
    for (int kc = 0; kc < 4; kc++) {
        __syncthreads();
        for (int i = tid; i < 8192; i += 256) {
            int k = i & 127, b2 = i >> 7;
            xs[k][b2] = x[(size_t)b2 * 262144 + (size_t)t * 512 + kc * 128 + k];
        }
        for (int i = tid; i < 4096; i += 256) {
            int r = i >> 7, k = i & 127;
            ww[r][k] = wih[(size_t)(rb + r) * 512 + kc * 128 + k];
        }
        __syncthreads();
        for (int k = 0; k < 128; k++) {
            float xv = xs[k][b];
#pragma unroll
            for (int rr = 0; rr < 8; rr++)
                acc[rr] = fmaf(ww[rw * 8 + rr][k], xv, acc[rr]);
        }
    }
#pragma unroll
    for (int rr = 0; rr < 8; rr++) {
        int rg = rb + rw * 8 + rr;
        int g = rg >> 9, j = rg & 511;
        gix[((size_t)((size_t)t * 512 + j) * 3 + g) * 64 + b] = acc[rr];
    }
}

// fallback transpose x -> xT[t][k][b]
__global__ void k_xtk(const float* __restrict__ x, float* __restrict__ xT) {
    __shared__ float tile[64][65];
    int t = blockIdx.x >> 3, kc = blockIdx.x & 7;
    int k = threadIdx.x & 63, b0 = threadIdx.x >> 6;
    for (int i = 0; i < 16; i++) {
        int b = i * 4 + b0;
        tile[k][b] = x[(size_t)b * 262144 + (size_t)t * 512 + kc * 64 + k];
    }
    __syncthreads();
    int b2 = threadIdx.x & 63, k0 = threadIdx.x >> 6;
    for (int i = 0; i < 16; i++) {
        int k2 = i * 4 + k0;
        xT[((size_t)t * 512 + kc * 64 + k2) * 64 + b2] = tile[k2][b2];
    }
}

// T1 = C2p * C1
__global__ void k_t1(const float* __restrict__ a1, const float* __restrict__ a2,
                     float* __restrict__ T1) {
    int l = blockIdx.x >> 10, c = blockIdx.x & 1023;
    int g = c >> 8, jj = c & 255;
    __shared__ float sA2[256];
    sA2[threadIdx.x] = a2[l * 65536 + jj * 256 + threadIdx.x];
    __syncthreads();
    const float* A1l = a1 + l * 262144;
    for (int colq = 0; colq < 4; colq++) {
        int col = colq * 256 + threadIdx.x;
        int half = col >> 9, cm = col & 511;
        float acc = 0.f;
#pragma unroll 4
        for (int q = 0; q < 64; q++) {
            int a0 = 2 * half;
            int j0 = g * 64 + q;
            acc = fmaf(sA2[4 * q + a0],     A1l[j0 * 512 + cm], acc);
            acc = fmaf(sA2[4 * q + a0 + 1], A1l[(j0 + 256) * 512 + cm], acc);
        }
        T1[((size_t)(l << 10) + c) * 1024 + col] = acc;
    }
}

// M = C3p * T1
__global__ void k_m(const float* __restrict__ a3, const float* __restrict__ T1,
                    float* __restrict__ M) {
    int l = blockIdx.x >> 10, c = blockIdx.x & 1023;
    int g = c >> 8, jj = c & 255;
    __shared__ float sA3[256];
    sA3[threadIdx.x] = a3[l * 65536 + jj * 256 + threadIdx.x];
    __syncthreads();
    const float* T1l = T1 + ((size_t)l << 20);
    for (int colq = 0; colq < 4; colq++) {
        int col = colq * 256 + threadIdx.x;
        float acc = 0.f;
#pragma unroll 4
        for (int m = 0; m < 256; m++) {
            int p = ((m & 3) << 8) + (g << 6) + (m >> 2);
            acc = fmaf(sA3[m], T1l[p * 1024 + col], acc);
        }
        M[((size_t)(l << 10) + c) * 1024 + col] = acc;
    }
}

// Persistent cooperative kernel. 256 blocks x 1024 threads, block owns 2 features.
// Exchange loads are 8B-paired agent atomics (halve L3 request count); C's h-half
// matvec partial is computed in B (which reads h' anyway) and carried in registers.
__global__ void __launch_bounds__(1024, 1)
persist(const float* __restrict__ x, const float* __restrict__ xT,
        const float* __restrict__ gix, int has_xt, int has_gix,
        const float* __restrict__ wih, const float* __restrict__ whh,
        const float* __restrict__ bih, const float* __restrict__ bhh,
        const float* __restrict__ Mc, const float* __restrict__ a4,
        float* __restrict__ ws, float* __restrict__ out) {
    __shared__ float wA[2][2][6][512];   // [l][f][d] d = gate*2+side (0=in,1=h)
    __shared__ float wM[2][4][1024];
    __shared__ float wD[2][2][1024];
    __shared__ float red2[12][16][64];
    __shared__ float bb[2][2][4];
    __shared__ float sH[2][2][64];       // [l][f][lane]

    const int tid = threadIdx.x, w = tid >> 6, lane = tid & 63, bid = blockIdx.x;

    for (int i = tid; i < 12288; i += 1024) {
        int l = i / 6144, r = i % 6144, f = r / 3072, r2 = r % 3072, d = r2 / 512, k = r2 & 511;
        int gate = d >> 1, side = d & 1;
        int j = 2 * bid + f;
        const float* src = side ? whh : wih;
        wA[l][f][d][k] = src[l * 786432 + (gate * 512 + j) * 512 + k];
    }
    for (int i = tid; i < 8192; i += 1024) {
        int l = i >> 12, r = (i >> 10) & 3, col = i & 1023;
        wM[l][r][col] = Mc[((size_t)(l << 10) + 4 * bid + r) * 1024 + col];
    }
    for (int i = tid; i < 4096; i += 1024) {
        int l = i >> 11, f = (i >> 10) & 1, k = i & 1023;
        wD[l][f][k] = a4[l * 524288 + (2 * bid + f) * 1024 + k];
    }
    if (tid < 16) {
        int l = tid / 8, f = (tid / 4) & 1, g = tid & 3;
        int j = 2 * bid + f;
        float v;
        if (g == 0)      v = bih[l * 1536 + j] + bhh[l * 1536 + j];
        else if (g == 1) v = bih[l * 1536 + 512 + j] + bhh[l * 1536 + 512 + j];
        else if (g == 2) v = bih[l * 1536 + 1024 + j];
        else             v = bhh[l * 1536 + 1024 + j];
        bb[l][f][g] = v;
    }
    __syncthreads();

    float* hsG = ws + OFF_HS;    // packed [l][256][64][2]
    float* hPg = ws + OFF_HP;    // packed
    float* sGg = ws + OFF_SG;    // [l][512][64]
    float* uG  = ws + OFF_U;     // packed [l][512][64][2]
    unsigned* flags = (unsigned*)(ws + OFF_CTR);   // 256 lines
    unsigned* genr  = flags + 8192;                // 16 lines
    unsigned bgen = 0;

    // ---- Stage A: GRU gates + h' ----
    auto stageA = [&](int l, int t) {
        float hprev = 0.f;
        if (w < 2) {
            int j = 2 * bid + w;
            hprev = ld_sc1(&hsG[(l << 15) + ((j >> 1) << 7) + (lane << 1) + (j & 1)]);
        }
        const float* hb = hsG + (l << 15);
        float* hPl = hPg + (l << 15);
        int k0 = w * 32;
        if (l == 0 && has_gix) {
            float acc[6] = {0.f, 0.f, 0.f, 0.f, 0.f, 0.f};
#pragma unroll 8
            for (int m = 0; m < 16; m++) {
                int k = k0 + 2 * m;
                float ha, hb2;
                ld2(&hb[(k >> 1) * 128 + lane * 2], ha, hb2);
#pragma unroll
                for (int f = 0; f < 2; f++) {
                    acc[f * 3 + 0] = fmaf(wA[0][f][1][k], ha, fmaf(wA[0][f][1][k + 1], hb2, acc[f * 3 + 0]));
                    acc[f * 3 + 1] = fmaf(wA[0][f][3][k], ha, fmaf(wA[0][f][3][k + 1], hb2, acc[f * 3 + 1]));
                    acc[f * 3 + 2] = fmaf(wA[0][f][5][k], ha, fmaf(wA[0][f][5][k + 1], hb2, acc[f * 3 + 2]));
                }
            }
#pragma unroll
            for (int u = 0; u < 6; u++) red2[u][w][lane] = acc[u];
            __syncthreads();
            if (w < 2) {
                int f = w, j = 2 * bid + f;
                float s0 = 0, s1 = 0, s2 = 0;
#pragma unroll
                for (int i = 0; i < 16; i++) {
                    s0 += red2[f * 3 + 0][i][lane];
                    s1 += red2[f * 3 + 1][i][lane];
                    s2 += red2[f * 3 + 2][i][lane];
                }
                const float* gx = gix + ((size_t)((size_t)t * 512 + j) * 3) * 64;
                float r = sigm(gx[lane] + s0 + bb[0][f][0]);
                float z = sigm(gx[64 + lane] + s1 + bb[0][f][1]);
                float n = tanhf(gx[128 + lane] + bb[0][f][2] + r * (s2 + bb[0][f][3]));
                float hp = (1.f - z) * n + z * hprev;
                sH[0][f][lane] = hp;
                st_sc1(&hPl[bid * 128 + lane * 2 + f], hp);
            }
        } else {
            float acc[12];
#pragma unroll
            for (int u = 0; u < 12; u++) acc[u] = 0.f;
#pragma unroll 8
            for (int m = 0; m < 16; m++) {
                int k = k0 + 2 * m;
                float ia, ib, ha, hb2;
                if (l == 1) {
                    ld2(&hsG[(k >> 1) * 128 + lane * 2], ia, ib);
                } else if (has_xt) {
                    ia = xT[(size_t)t * 32768 + k * 64 + lane];
                    ib = xT[(size_t)t * 32768 + (k + 1) * 64 + lane];
                } else {
                    ia = x[(size_t)lane * 262144 + (size_t)t * 512 + k];
                    ib = x[(size_t)lane * 262144 + (size_t)t * 512 + k + 1];
                }
                ld2(&hb[(k >> 1) * 128 + lane * 2], ha, hb2);
#pragma unroll
                for (int f = 0; f < 2; f++) {
                    acc[f * 6 + 0] = fmaf(wA[l][f][0][k], ia, fmaf(wA[l][f][0][k + 1], ib, acc[f * 6 + 0]));
                    acc[f * 6 + 1] = fmaf(wA[l][f][1][k], ha, fmaf(wA[l][f][1][k + 1], hb2, acc[f * 6 + 1]));
                    acc[f * 6 + 2] = fmaf(wA[l][f][2][k], ia, fmaf(wA[l][f][2][k + 1], ib, acc[f * 6 + 2]));
                    acc[f * 6 + 3] = fmaf(wA[l][f][3][k], ha, fmaf(wA[l][f][3][k + 1], hb2, acc[f * 6 + 3]));
                    acc[f * 6 + 4] = fmaf(wA[l][f][4][k], ia, fmaf(wA[l][f][4][k + 1], ib, acc[f * 6 + 4]));
                    acc[f * 6 + 5] = fmaf(wA[l][f][5][k], ha, fmaf(wA[l][f][5][k + 1], hb2, acc[f * 6 + 5]));
                }
            }
#pragma unroll
            for (int u = 0; u < 12; u++) red2[u][w][lane] = acc[u];
            __syncthreads();
            if (w < 2) {
                int f = w, j = 2 * bid + f;
                float g0 = 0, g1 = 0, g2 = 0, g3 = 0, g4 = 0, g5 = 0;
#pragma unroll
                for (int i = 0; i < 16; i++) {
                    g0 += red2[f * 6 + 0][i][lane]; g1 += red2[f * 6 + 1][i][lane];
                    g2 += red2[f * 6 + 2][i][lane]; g3 += red2[f * 6 + 3][i][lane];
                    g4 += red2[f * 6 + 4][i][lane]; g5 += red2[f * 6 + 5][i][lane];
                }
                float r = sigm(g0 + g1 + bb[l][f][0]);
                float z = sigm(g2 + g3 + bb[l][f][1]);
                float n = tanhf(g4 + bb[l][f][2] + r * (g5 + bb[l][f][3]));
                float hp = (1.f - z) * n + z * hprev;
                sH[l][f][lane] = hp;
                st_sc1(&hPl[bid * 128 + lane * 2 + f], hp);
            }
        }
    };

    // ---- Stage B: ranks + h-half partial of C's matvec (accB[4], kept in regs) ----
    auto stageB = [&](int l, float* accB) {
        int j0 = 2 * bid, j1 = j0 + 1;
        float v0 = sH[l][0][lane], v1 = sH[l][1][lane];
        const float* hPl = hPg + (l << 15);
        float* sGl = sGg + (l << 15);
        int k0 = w * 32, cnt0 = 0, cnt1 = 0;
        accB[0] = accB[1] = accB[2] = accB[3] = 0.f;
#pragma unroll 8
        for (int m = 0; m < 16; m++) {
            int k = k0 + 2 * m;
            float ha, hb2;
            ld2(&hPl[(k >> 1) * 128 + lane * 2], ha, hb2);
            cnt0 += (ha < v0 || (ha == v0 && k < j0)) ? 1 : 0;
            cnt0 += (hb2 < v0 || (hb2 == v0 && k + 1 < j0)) ? 1 : 0;
            cnt1 += (ha < v1 || (ha == v1 && k < j1)) ? 1 : 0;
            cnt1 += (hb2 < v1 || (hb2 == v1 && k + 1 < j1)) ? 1 : 0;
#pragma unroll
            for (int r = 0; r < 4; r++)
                accB[r] = fmaf(wM[l][r][k], ha, fmaf(wM[l][r][k + 1], hb2, accB[r]));
        }
        red2[0][w][lane] = (float)cnt0;
        red2[1][w][lane] = (float)cnt1;
        __syncthreads();
        if (w < 2) {
            int rk = 0;
#pragma unroll
            for (int i = 0; i < 16; i++) rk += (int)red2[w][i][lane];
            st_sc1(&sGl[rk * 64 + lane], sH[l][w][lane]);
        }
    };

    // ---- Stage C: u = relu(M [h; s]); s-half only (h-half from accB) ----
    auto stageC = [&](int l, const float* accB) {
        float acc[4] = {accB[0], accB[1], accB[2], accB[3]};
        int s0 = w * 32;
        const float* sGl = sGg + (l << 15);
#pragma unroll 8
        for (int ss = 0; ss < 32; ss++) {
            int sp = s0 + ss;
            float vv = ld_sc1(&sGl[sp * 64 + lane]);
#pragma unroll
            for (int r = 0; r < 4; r++)
                acc[r] = fmaf(wM[l][r][512 + sp], vv, acc[r]);
        }
#pragma unroll
        for (int r = 0; r < 4; r++) red2[r][w][lane] = acc[r];
        __syncthreads();
        if (w < 2) {
            float sa = 0.f, sb = 0.f;
#pragma unroll
            for (int i = 0; i < 16; i++) {
                sa += red2[2 * w + 0][i][lane];
                sb += red2[2 * w + 1][i][lane];
            }
            // u rows (4*bid + 2w, 4*bid + 2w + 1) -> packed pair
            st2(&uG[(l << 16) + (2 * bid + w) * 128 + lane * 2],
                fmaxf(sa, 0.f), fmaxf(sb, 0.f));
        }
    };

    // ---- Stage D: scores + state update ----
    auto stageD = [&](int l, int t) {
        float a0 = 0.f, a1v = 0.f;
        int k0 = w * 64;
        const float* uL = uG + (l << 16);
#pragma unroll 8
        for (int m = 0; m < 32; m++) {
            int k = k0 + 2 * m;
            float ua, ub;
            ld2(&uL[(k >> 1) * 128 + lane * 2], ua, ub);
            a0 = fmaf(wD[l][0][k], ua, fmaf(wD[l][0][k + 1], ub, a0));
            a1v = fmaf(wD[l][1][k], ua, fmaf(wD[l][1][k + 1], ub, a1v));
        }
        red2[0][w][lane] = a0;
        red2[1][w][lane] = a1v;
        __syncthreads();
        if (w < 2) {
            float s = 0.f;
#pragma unroll
            for (int i = 0; i < 16; i++) s += red2[w][i][lane];
            float hnew = sH[l][w][lane] * sigm(s);
            int j = 2 * bid + w;
            st_sc1(&hsG[(l << 15) + bid * 128 + lane * 2 + w], hnew);
            if (l == 1)
                out[(size_t)lane * 262144 + (size_t)t * 512 + j] = hnew;
        }
    };

    float accB0[4], accB1[4];

    // Pipelined main loop: iteration t runs (layer0, t) and (layer1, t-1).
    for (int t = 0; t <= 512; t++) {
        const int t0 = t, t1 = t - 1;
        const bool do0 = (t0 < 512), do1 = (t1 >= 0);

        if (do0) stageA(0, t0);
        if (do1) { __syncthreads(); stageA(1, t1); }
        gbar(flags, genr, ++bgen);

        if (do0) stageB(0, accB0);
        if (do1) { __syncthreads(); stageB(1, accB1); }
        gbar(flags, genr, ++bgen);

        if (do0) stageC(0, accB0);
        if (do1) { __syncthreads(); stageC(1, accB1); }
        gbar(flags, genr, ++bgen);

        if (do0) stageD(0, t0);
        if (do1) { __syncthreads(); stageD(1, t1); }
        gbar(flags, genr, ++bgen);
    }
}

extern "C" void kernel_launch(void* const* d_in, const int* in_sizes, int n_in,
                              void* d_out, int out_size, void* d_ws, size_t ws_size,
                              hipStream_t stream) {
    const float* x   = (const float*)d_in[0];
    const float* h0  = (const float*)d_in[1];
    const float* wih = (const float*)d_in[2];
    const float* whh = (const float*)d_in[3];
    const float* bih = (const float*)d_in[4];
    const float* bhh = (const float*)d_in[5];
    const float* a1  = (const float*)d_in[6];
    const float* a2  = (const float*)d_in[7];
    const float* a3  = (const float*)d_in[8];
    const float* a4  = (const float*)d_in[9];
    float* ws  = (float*)d_ws;
    float* out = (float*)d_out;

    int has_gix = (ws_size >= (size_t)WS_GIX * 4) ? 1 : 0;
    int has_xt  = (!has_gix && ws_size >= (size_t)WS_XT * 4) ? 1 : 0;
    float* T1p = ws + OFF_T1;
    float* Mp  = ws + OFF_M;
    const float* gixp = ws + OFF_GIX;
    const float* xTp  = ws + OFF_XT;

    hipLaunchKernelGGL(k_init, dim3(256), dim3(256), 0, stream, h0, ws);
    if (has_gix)
        hipLaunchKernelGGL(k_gix, dim3(512, 48), dim3(256), 0, stream, x, wih, ws + OFF_GIX);
    else if (has_xt)
        hipLaunchKernelGGL(k_xtk, dim3(4096), dim3(256), 0, stream, x, ws + OFF_XT);
    hipLaunchKernelGGL(k_t1, dim3(2048), dim3(256), 0, stream, a1, a2, T1p);
    hipLaunchKernelGGL(k_m, dim3(2048), dim3(256), 0, stream, a3, T1p, Mp);

    void* args[] = {(void*)&x, (void*)&xTp, (void*)&gixp, (void*)&has_xt, (void*)&has_gix,
                    (void*)&wih, (void*)&whh, (void*)&bih, (void*)&bhh,
                    (void*)&Mp, (void*)&a4, (void*)&ws, (void*)&out};
    hipLaunchCooperativeKernel((void*)persist, dim3(256), dim3(1024), args, 0, stream);
}